// Round 1
// baseline (838.948 us; speedup 1.0000x reference)
//
#include <hip/hip_runtime.h>
#include <stdint.h>
#include <stddef.h>

// ---------------------------------------------------------------------------
// Linear-attention GAT layer, MI355X bf16-MFMA implementation.
//   Q = elu(h@Wq)+1 ; K = elu(h@Wk)+1 ; V = h@Wv
//   KV = K^T@V ; ksum = colsum(K) ; out = elu((Q@KV) / (Q@ksum))
// N=200000, DIN=512, DOUT=128. h read once; Q spilled as bf16; KV via
// register-resident per-block partials (512) + reduce; no atomics.
// ---------------------------------------------------------------------------

typedef __attribute__((ext_vector_type(8))) short bf16x8;   // 8 bf16 = 4 VGPR
typedef __attribute__((ext_vector_type(4))) short bf16x4;   // 8 B
typedef __attribute__((ext_vector_type(4))) float f32x4;

#define NROWS   200000
#define DIN     512
#define DOUT    128
#define NCHUNK  3125      // NROWS / 64
#define PA_BLOCKS 512

#define MFMA16(A, B, C) __builtin_amdgcn_mfma_f32_16x16x32_bf16(A, B, C, 0, 0, 0)

__device__ __forceinline__ short f2bf(float f) {
  unsigned u = __builtin_bit_cast(unsigned, f);
  u = (u + 0x7fffu + ((u >> 16) & 1u)) >> 16;   // RNE
  return (short)u;
}
__device__ __forceinline__ float bf2f(short b) {
  unsigned u = ((unsigned)(unsigned short)b) << 16;
  return __builtin_bit_cast(float, u);
}

// ---------------------------------------------------------------------------
// Kernel 1: W_Q|W_K|W_V (f32 [512][128] row-major) -> wt bf16 [384 cols][512 k]
// ---------------------------------------------------------------------------
__global__ void prep_wt(const float* __restrict__ wq, const float* __restrict__ wk,
                        const float* __restrict__ wv, short* __restrict__ wt) {
  int gid = blockIdx.x * 256 + threadIdx.x;   // 0..49151
  int k   = gid >> 5;                          // 0..1535 (which*512 + kk)
  int j4  = (gid & 31) * 4;
  int which = k >> 9;
  int kk    = k & 511;
  const float* W = (which == 0) ? wq : (which == 1) ? wk : wv;
  f32x4 v = *(const f32x4*)(W + (size_t)kk * DOUT + j4);
#pragma unroll
  for (int e = 0; e < 4; ++e)
    wt[(size_t)(which * DOUT + j4 + e) * DIN + kk] = f2bf(v[e]);
}

// ---------------------------------------------------------------------------
// Kernel 2: fused QKV GEMM + elu + Q store + per-block KV/ksum partials.
// 512 threads = 8 waves; wave w owns 16-col tiles {w (Q), w+8 (K), w+16 (V)}
// over the chunk's 64 rows. 16x16x32 bf16 MFMA. BK=32, 1-step reg prefetch.
// LDS (32 KB union):  A [64 rows][32 k] bf16 swz @0 (4 KB), B [384 c][32 k]
// swz @4096 (24 KB); chunk epilogue reuses [0,32K) as K^T/V staging
// [128 c][64 r] bf16 swz.
// ---------------------------------------------------------------------------
__global__ __launch_bounds__(512, 2) void pass_a(
    const float* __restrict__ h, const short* __restrict__ wt,
    short* __restrict__ q_ws, float* __restrict__ kv_part,
    float* __restrict__ ksum_part) {
  __shared__ __attribute__((aligned(16))) char smem[32768];
  const int tid = threadIdx.x;
  const int w  = tid >> 6;
  const int l  = tid & 63;
  const int lq = l >> 4;     // k-quadrant
  const int lr = l & 15;     // row/col within 16-tile
  const int bid = blockIdx.x;

  // --- A staging (this thread writes 4 h-elems as bf16x4, swizzled) ---
  const int arow = tid >> 3;                 // 0..63
  const int akq  = tid & 7;                  // 4-elem group within 32 k
  const int sxa  = (arow ^ (arow >> 2)) & 3;
  char* const a_wptr = smem + arow * 64 +
      ((((akq >> 1) ^ sxa) & 3) << 4) + (akq & 1) * 8;

  // --- fragment-read bases (swizzle nibble is lane-only: rows/cols = x*16+lr)
  const int sxl = (lr ^ (lr >> 2)) & 3;
  const char* const a_rbase = smem + lr * 64 + (((lq ^ sxl) & 3) << 4);
  const char* const b_rbase = smem + 4096 + lr * 64 + (((lq ^ sxl) & 3) << 4);

  // --- B staging constants (3 chunks of 16 B per thread per K-step) ---
  int b_dst[3], b_src[3];
#pragma unroll
  for (int q = 0; q < 3; ++q) {
    int cc  = q * 512 + tid;        // 0..1535 linear 16B chunk in LDS
    int col = cc >> 2;
    int sl  = cc & 3;
    int sx  = (col ^ (col >> 2)) & 3;
    b_dst[q] = 4096 + cc * 16;
    b_src[q] = col * DIN + ((sl ^ sx) & 3) * 8;   // + t*32 at use
  }

  const f32x4 zero4 = {0.f, 0.f, 0.f, 0.f};
  f32x4 kvacc[8];
#pragma unroll
  for (int jt = 0; jt < 8; ++jt) kvacc[jt] = zero4;
  float ksum_acc = 0.f;

  for (int c = bid; c < NCHUNK; c += PA_BLOCKS) {
    f32x4 accQ[4], accK[4], accV[4];
#pragma unroll
    for (int rt = 0; rt < 4; ++rt) { accQ[rt] = zero4; accK[rt] = zero4; accV[rt] = zero4; }

    const float* hrow = h + (size_t)(c * 64 + arow) * DIN + akq * 4;
    f32x4  aReg  = *(const f32x4*)(hrow);
    bf16x8 bReg0 = *(const bf16x8*)(wt + b_src[0]);
    bf16x8 bReg1 = *(const bf16x8*)(wt + b_src[1]);
    bf16x8 bReg2 = *(const bf16x8*)(wt + b_src[2]);

    for (int t = 0; t < 16; ++t) {
      __syncthreads();                       // prior phase's LDS reads done
      bf16x4 a4;
      a4[0] = f2bf(aReg[0]); a4[1] = f2bf(aReg[1]);
      a4[2] = f2bf(aReg[2]); a4[3] = f2bf(aReg[3]);
      *(bf16x4*)a_wptr = a4;
      *(bf16x8*)(smem + b_dst[0]) = bReg0;
      *(bf16x8*)(smem + b_dst[1]) = bReg1;
      *(bf16x8*)(smem + b_dst[2]) = bReg2;
      __syncthreads();
      if (t < 15) {                          // prefetch next step (hides HBM/L2)
        aReg  = *(const f32x4*)(hrow + (t + 1) * 32);
        bReg0 = *(const bf16x8*)(wt + b_src[0] + (t + 1) * 32);
        bReg1 = *(const bf16x8*)(wt + b_src[1] + (t + 1) * 32);
        bReg2 = *(const bf16x8*)(wt + b_src[2] + (t + 1) * 32);
      }
      bf16x8 af[4];
#pragma unroll
      for (int rt = 0; rt < 4; ++rt)
        af[rt] = *(const bf16x8*)(a_rbase + rt * 1024);
      bf16x8 bq = *(const bf16x8*)(b_rbase + (w)      * 1024);
      bf16x8 bk = *(const bf16x8*)(b_rbase + (w + 8)  * 1024);
      bf16x8 bv = *(const bf16x8*)(b_rbase + (w + 16) * 1024);
#pragma unroll
      for (int rt = 0; rt < 4; ++rt) {
        accQ[rt] = MFMA16(af[rt], bq, accQ[rt]);
        accK[rt] = MFMA16(af[rt], bk, accK[rt]);
        accV[rt] = MFMA16(af[rt], bv, accV[rt]);
      }
    }

    // ---- chunk epilogue: elu+1, Q store, ksum, K^T/V -> LDS, KV MFMA ----
    const int qcol = w * 16 + lr;
    float ks = 0.f;
#pragma unroll
    for (int rt = 0; rt < 4; ++rt) {
      f32x4 qe, ke;
#pragma unroll
      for (int f = 0; f < 4; ++f) {
        float x = accQ[rt][f];
        qe[f] = (x > 0.f) ? (x + 1.f) : __expf(x);
        float y = accK[rt][f];
        ke[f] = (y > 0.f) ? (y + 1.f) : __expf(y);
      }
      short* qp = q_ws + (size_t)(c * 64 + rt * 16 + lq * 4) * DOUT + qcol;
      qp[0]        = f2bf(qe[0]);
      qp[DOUT]     = f2bf(qe[1]);
      qp[2 * DOUT] = f2bf(qe[2]);
      qp[3 * DOUT] = f2bf(qe[3]);
      ks += ke[0] + ke[1] + ke[2] + ke[3];
      bf16x4 kp, vp;
#pragma unroll
      for (int f = 0; f < 4; ++f) { kp[f] = f2bf(ke[f]); vp[f] = f2bf(accV[rt][f]); }
      const int i  = w * 16 + lr;            // K/V column index 0..127
      const int wb = i * 128 +
          ((((rt * 2 + (lq >> 1)) ^ (lr & 7)) & 7) << 4) + (lq & 1) * 8;
      *(bf16x4*)(smem + wb)          = kp;   // k_lds [col][row] swz
      *(bf16x4*)(smem + 16384 + wb)  = vp;   // v_lds
    }
    ks += __shfl_xor(ks, 16);
    ks += __shfl_xor(ks, 32);
    ksum_acc += ks;
    __syncthreads();
    // wave w computes KV rows [16w,16w+16) x all 128 V-cols, K-dim = 64 rows
#pragma unroll
    for (int ksb = 0; ksb < 2; ++ksb) {
      const int rslot = ((ksb * 4 + lq) ^ (lr & 7)) & 7;
      bf16x8 ka = *(const bf16x8*)(smem + (w * 16 + lr) * 128 + (rslot << 4));
#pragma unroll
      for (int jt = 0; jt < 8; ++jt) {
        bf16x8 vb = *(const bf16x8*)(smem + 16384 + (jt * 16 + lr) * 128 + (rslot << 4));
        kvacc[jt] = MFMA16(ka, vb, kvacc[jt]);
      }
    }
    __syncthreads();
  }

  // ---- per-block partials ----
  float* kvp = kv_part + (size_t)bid * 16384;
#pragma unroll
  for (int jt = 0; jt < 8; ++jt)
#pragma unroll
    for (int f = 0; f < 4; ++f)
      kvp[(w * 16 + lq * 4 + f) * 128 + jt * 16 + lr] = kvacc[jt][f];
  if (lq == 0) ksum_part[bid * 128 + w * 16 + lr] = ksum_acc;
}

// ---------------------------------------------------------------------------
// Kernel 3: reduce 512 KV partials -> kvT bf16 [j][i] PRE-SWIZZLED for pass_c
// LDS image; reduce ksum partials. Grid 129 x 128.
// ---------------------------------------------------------------------------
__global__ void reduce_kv(const float* __restrict__ kv_part,
                          const float* __restrict__ ksum_part,
                          short* __restrict__ kvT, float* __restrict__ ksum) {
  if (blockIdx.x < 128) {
    const int i  = blockIdx.x;
    const int t  = threadIdx.x;
    const int j4 = t & 31;
    const int bs = t >> 5;
    f32x4 acc = {0.f, 0.f, 0.f, 0.f};
#pragma unroll 4
    for (int b = bs * 128; b < bs * 128 + 128; ++b)
      acc += *(const f32x4*)(kv_part + (size_t)b * 16384 + i * 128 + j4 * 4);
    __shared__ f32x4 red[4][32];
    red[bs][j4] = acc;
    __syncthreads();
    if (t < 32) {
      f32x4 s = red[0][t] + red[1][t] + red[2][t] + red[3][t];
#pragma unroll
      for (int e = 0; e < 4; ++e) {
        int j = t * 4 + e;
        kvT[j * 128 + (i ^ ((j & 7) << 3))] = f2bf(s[e]);  // swizzled element
      }
    }
  } else {
    const int j = threadIdx.x;
    float s = 0.f;
#pragma unroll 8
    for (int b = 0; b < PA_BLOCKS; ++b) s += ksum_part[b * 128 + j];
    ksum[j] = s;
  }
}

// ---------------------------------------------------------------------------
// Kernel 4: out = elu( (Q@KV) / (Q@ksum) ).  3125 blocks x 256 thr (4 waves,
// 16 rows each). Q A-frags straight from global (full 64B sectors); KV bf16
// in LDS (linear copy of pre-swizzled image); denom in f32 VALU + shfl.
// ---------------------------------------------------------------------------
__global__ __launch_bounds__(256, 4) void pass_c(
    const short* __restrict__ q_ws, const short* __restrict__ kvT,
    const float* __restrict__ ksum, float* __restrict__ out) {
  __shared__ __attribute__((aligned(16))) char smem[33024];   // 32K kv + 64 f32 denom
  const int tid = threadIdx.x;
  const int w  = tid >> 6, l = tid & 63, lq = l >> 4, lr = l & 15;
  const int rowbase = blockIdx.x * 64 + w * 16;

#pragma unroll
  for (int q = 0; q < 8; ++q) {
    int cc = q * 256 + tid;
    *(bf16x8*)(smem + cc * 16) = *(const bf16x8*)(kvT + cc * 8);
  }

  bf16x8 qa[4];
  float d = 0.f;
  const short* qrow = q_ws + (size_t)(rowbase + lr) * DOUT + lq * 8;
#pragma unroll
  for (int ks = 0; ks < 4; ++ks) {
    qa[ks] = *(const bf16x8*)(qrow + ks * 32);
    f32x4 k0 = *(const f32x4*)(ksum + ks * 32 + lq * 8);
    f32x4 k1 = *(const f32x4*)(ksum + ks * 32 + lq * 8 + 4);
#pragma unroll
    for (int e = 0; e < 4; ++e) d += bf2f(qa[ks][e]) * k0[e];
#pragma unroll
    for (int e = 0; e < 4; ++e) d += bf2f(qa[ks][e + 4]) * k1[e];
  }
  d += __shfl_xor(d, 16);
  d += __shfl_xor(d, 32);
  float* dlds = (float*)(smem + 32768);
  if (l < 16) dlds[w * 16 + lr] = d;
  __syncthreads();

  const f32x4 zero4 = {0.f, 0.f, 0.f, 0.f};
  f32x4 acc[8];
#pragma unroll
  for (int jt = 0; jt < 8; ++jt) acc[jt] = zero4;
#pragma unroll
  for (int ks = 0; ks < 4; ++ks) {
#pragma unroll
    for (int jt = 0; jt < 8; ++jt) {
      const int j    = jt * 16 + lr;
      const int slot = (ks * 4 + lq) ^ (lr & 7);   // XOR hits bits 0-2 only
      bf16x8 bv = *(const bf16x8*)(smem + j * 256 + (slot << 4));
      acc[jt] = MFMA16(qa[ks], bv, acc[jt]);
    }
  }
  float z[4];
#pragma unroll
  for (int f = 0; f < 4; ++f) z[f] = 1.f / dlds[w * 16 + lq * 4 + f];
#pragma unroll
  for (int jt = 0; jt < 8; ++jt) {
#pragma unroll
    for (int f = 0; f < 4; ++f) {
      float v = acc[jt][f] * z[f];
      v = (v > 0.f) ? v : (__expf(v) - 1.f);
      out[(size_t)(rowbase + lq * 4 + f) * DOUT + jt * 16 + lr] = v;
    }
  }
}

// ---------------------------------------------------------------------------
// Workspace layout (bytes):
//   [0,          51200000)  q_ws      bf16 N x 128
//   [51200000,   51593216)  wt        bf16 384 x 512
//   [51593216,   85147648)  kv_part   f32  512 x 128 x 128
//   [85147648,   85409792)  ksum_part f32  512 x 128
//   [85409792,   85442560)  kvT       bf16 128 x 128 (pre-swizzled)
//   [85442560,   85443072)  ksum      f32  128
// total 85,443,072 B
// ---------------------------------------------------------------------------
extern "C" void kernel_launch(void* const* d_in, const int* in_sizes, int n_in,
                              void* d_out, int out_size, void* d_ws, size_t ws_size,
                              hipStream_t stream) {
  const float* h  = (const float*)d_in[0];
  const float* wq = (const float*)d_in[1];
  const float* wk = (const float*)d_in[2];
  const float* wv = (const float*)d_in[3];
  char* ws = (char*)d_ws;
  short* q_ws      = (short*)(ws);
  short* wt        = (short*)(ws + 51200000);
  float* kv_part   = (float*)(ws + 51593216);
  float* ksum_part = (float*)(ws + 85147648);
  short* kvT       = (short*)(ws + 85409792);
  float* ksum      = (float*)(ws + 85442560);
  float* out       = (float*)d_out;

  prep_wt<<<dim3(192), dim3(256), 0, stream>>>(wq, wk, wv, wt);
  pass_a<<<dim3(PA_BLOCKS), dim3(512), 0, stream>>>(h, wt, q_ws, kv_part, ksum_part);
  reduce_kv<<<dim3(129), dim3(128), 0, stream>>>(kv_part, ksum_part, kvT, ksum);
  pass_c<<<dim3(NCHUNK), dim3(256), 0, stream>>>(q_ws, kvT, ksum, out);
}

// Round 2
// 748.448 us; speedup vs baseline: 1.1209x; 1.1209x over previous
//
#include <hip/hip_runtime.h>
#include <stdint.h>
#include <stddef.h>

// ---------------------------------------------------------------------------
// Linear-attention GAT layer, MI355X bf16-MFMA, v2 (streaming structure).
//   Q = elu(h@Wq)+1 ; K = elu(h@Wk)+1 ; V = h@Wv        (pass_a, z per block)
//   KV = K^T@V ; ksum = colsum(K)                        (pass_b + reduce)
//   out = elu((Q@KV) * (1/(Q@ksum)))                     (pass_c)
// pass_a: B-panel (128 cols x 512 k bf16 = 131KB) resident in LDS, loaded
// ONCE per block (global_load_lds, pre-swizzled image); waves own exclusive
// 32-row strips; A-frags direct from global; ZERO main-loop barriers.
// ---------------------------------------------------------------------------

typedef __attribute__((ext_vector_type(8))) short bf16x8;
typedef __attribute__((ext_vector_type(4))) float f32x4;

#define NROWS   200000
#define DIN     512
#define DOUT    128

#define MFMA16(A, B, C) __builtin_amdgcn_mfma_f32_16x16x32_bf16(A, B, C, 0, 0, 0)

__device__ __forceinline__ short f2bf(float f) {
  unsigned u = __builtin_bit_cast(unsigned, f);
  u = (u + 0x7fffu + ((u >> 16) & 1u)) >> 16;   // RNE
  return (short)u;
}
__device__ __forceinline__ float bf2f(short b) {
  unsigned u = ((unsigned)(unsigned short)b) << 16;
  return __builtin_bit_cast(float, u);
}

// ---------------------------------------------------------------------------
// Kernel 1: build wt image: [z][col 0..127][1KB row of 64 16B-slots], where
// k-group s (8 bf16) of col c sits at slot s ^ (c&7).  (swizzle baked into
// global so pass_a can global_load_lds LINEARLY and ds_read swizzled.)
// Grid 96 x 256: thread = (z, col, s).
// ---------------------------------------------------------------------------
__global__ void prep_wt(const float* __restrict__ wq, const float* __restrict__ wk,
                        const float* __restrict__ wv, short* __restrict__ wt) {
  int gid = blockIdx.x * 256 + threadIdx.x;   // 0..24575
  int z   = gid >> 13;
  int col = (gid >> 6) & 127;
  int s   = gid & 63;
  const float* W = (z == 0) ? wq : (z == 1) ? wk : wv;
  bf16x8 o;
#pragma unroll
  for (int e = 0; e < 8; ++e)
    o[e] = f2bf(W[(size_t)(s * 8 + e) * DOUT + col]);
  *(bf16x8*)((char*)wt + (size_t)z * 131072 + col * 1024 + ((s ^ (col & 7)) * 16)) = o;
}

// ---------------------------------------------------------------------------
// Kernel 2: one of Q/K/V per block (z). 512 thr = 8 waves; wave owns rows
// [tile*256 + w*32, +32), all 128 cols. 16x16x32 MFMA, R=2 row-frags, C=8.
// Main loop: 16 K-steps (BK=32), A from global f32 (cvt in reg), B from
// LDS-resident panel. No barriers after the panel load.
// XCD swizzle: trio (Q,K,V of same row-tile) adjacent on one XCD.
// ---------------------------------------------------------------------------
__global__ __launch_bounds__(512) void pass_a(
    const float* __restrict__ h, const short* __restrict__ wt,
    short* __restrict__ q_ws, short* __restrict__ k_ws, short* __restrict__ v_ws) {
  extern __shared__ __attribute__((aligned(16))) char smem[];   // 131072

  // --- block -> (tile, z) with trio-on-one-XCD swizzle. grid = 2352 ---
  const int bid  = blockIdx.x;
  const int xcd  = bid & 7;
  const int slot = bid >> 3;               // 0..293
  const int nT   = (xcd < 6) ? 98 : 97;    // trios on this xcd
  if ((slot / 3) >= nT) return;            // dead tail blocks (uniform exit)
  const int base = (xcd < 6) ? xcd * 98 : 6 * 98 + (xcd - 6) * 97;
  const int tile = base + slot / 3;        // 0..781
  const int z    = slot % 3;               // 0=Q 1=K 2=V

  const int tid = threadIdx.x;
  const int wv  = tid >> 6;
  const int l   = tid & 63;
  const int lr  = l & 15;
  const int lq  = l >> 4;

  // --- load 131072B panel into LDS linearly (wave-uniform base + lane*16) ---
  {
    const char* src = (const char*)wt + (size_t)z * 131072;
    typedef const __attribute__((address_space(1))) char glb_c;
    typedef __attribute__((address_space(3))) char lds_c;
#pragma unroll
    for (int r = 0; r < 16; ++r) {
      int off = r * 8192 + (wv * 64) * 16;      // wave-uniform part
      __builtin_amdgcn_global_load_lds((glb_c*)(src + off + l * 16),
                                       (lds_c*)(smem + off), 16, 0, 0);
    }
  }
  __syncthreads();   // drains vmcnt; panel resident for the whole kernel

  // --- A addressing: two 16-row fragments per wave ---
  size_t row0 = (size_t)tile * 256 + wv * 32 + lr;
  size_t row1 = row0 + 16;
  size_t r0c = (row0 < NROWS) ? row0 : (size_t)(NROWS - 1);
  size_t r1c = (row1 < NROWS) ? row1 : (size_t)(NROWS - 1);
  const float* a0p = h + r0c * DIN + lq * 8;    // + ks*32 per step
  const float* a1p = h + r1c * DIN + lq * 8;

  f32x4 acc[2][8];
#pragma unroll
  for (int rt = 0; rt < 2; ++rt)
#pragma unroll
    for (int ct = 0; ct < 8; ++ct) acc[rt][ct] = (f32x4){0.f, 0.f, 0.f, 0.f};

  // prologue loads (depth-1 software pipeline)
  f32x4 c00 = *(const f32x4*)(a0p),     c01 = *(const f32x4*)(a0p + 4);
  f32x4 c10 = *(const f32x4*)(a1p),     c11 = *(const f32x4*)(a1p + 4);

  for (int ks = 0; ks < 16; ++ks) {
    f32x4 n00, n01, n10, n11;
    if (ks < 15) {
      n00 = *(const f32x4*)(a0p + (ks + 1) * 32);
      n01 = *(const f32x4*)(a0p + (ks + 1) * 32 + 4);
      n10 = *(const f32x4*)(a1p + (ks + 1) * 32);
      n11 = *(const f32x4*)(a1p + (ks + 1) * 32 + 4);
    }
    bf16x8 af0, af1;
#pragma unroll
    for (int e = 0; e < 4; ++e) {
      af0[e] = f2bf(c00[e]); af0[e + 4] = f2bf(c01[e]);
      af1[e] = f2bf(c10[e]); af1[e + 4] = f2bf(c11[e]);
    }
#pragma unroll
    for (int ct = 0; ct < 8; ++ct) {
      const int col  = ct * 16 + lr;
      const int s    = (ks * 4 + lq) ^ (l & 7);       // col&7 == l&7
      bf16x8 bf = *(const bf16x8*)(smem + col * 1024 + s * 16);
      acc[0][ct] = MFMA16(af0, bf, acc[0][ct]);
      acc[1][ct] = MFMA16(af1, bf, acc[1][ct]);
    }
    c00 = n00; c01 = n01; c10 = n10; c11 = n11;
  }

  // --- epilogue: elu (z<2: elu(x)+1 ; z==2: identity), bf16 store ---
  short* dst = (z == 0) ? q_ws : (z == 1) ? k_ws : v_ws;
  const bool isV = (z == 2);
#pragma unroll
  for (int rt = 0; rt < 2; ++rt) {
    size_t rbase = (size_t)tile * 256 + wv * 32 + rt * 16 + lq * 4;
#pragma unroll
    for (int ct = 0; ct < 8; ++ct) {
      const int col = ct * 16 + lr;
#pragma unroll
      for (int f = 0; f < 4; ++f) {
        size_t row = rbase + f;
        if (row < NROWS) {
          float x = acc[rt][ct][f];
          float y = isV ? x : ((x > 0.f) ? (x + 1.f) : __expf(x));
          dst[row * DOUT + col] = f2bf(y);
        }
      }
    }
  }
}

// ---------------------------------------------------------------------------
// Kernel 3: KV = K^T @ V partials + ksum partials. 256 blocks x 256 thr
// (4 waves). Chunks of 32 rows (6250 total, grid-stride). K,V staged
// TRANSPOSED in LDS ([c][r], 40-short rows -> <=2-way conflicts), one
// 16x16x32 K-step per chunk. Wave w owns KV rows [32w,32w+32) x 128 cols.
// ---------------------------------------------------------------------------
__global__ __launch_bounds__(256) void pass_b(
    const short* __restrict__ k_ws, const short* __restrict__ v_ws,
    float* __restrict__ kv_part, float* __restrict__ ksum_part) {
  __shared__ short KT[128 * 40];
  __shared__ short VT[128 * 40];
  __shared__ float kred[32][128];

  const int tid = threadIdx.x;
  const int w   = tid >> 6;
  const int l   = tid & 63;
  const int lr  = l & 15;
  const int lq  = l >> 4;
  const int r   = tid >> 3;          // 0..31 (staging row)
  const int c0  = (tid & 7) * 16;    // staging col group

  f32x4 acc[2][8];
#pragma unroll
  for (int rt = 0; rt < 2; ++rt)
#pragma unroll
    for (int ct = 0; ct < 8; ++ct) acc[rt][ct] = (f32x4){0.f, 0.f, 0.f, 0.f};
  float ksa[16];
#pragma unroll
  for (int e = 0; e < 16; ++e) ksa[e] = 0.f;

  for (int c = blockIdx.x; c < 6250; c += 256) {
    size_t rowb = (size_t)c * 32 + r;
    bf16x8 k0 = *(const bf16x8*)(k_ws + rowb * DOUT + c0);
    bf16x8 k1 = *(const bf16x8*)(k_ws + rowb * DOUT + c0 + 8);
    bf16x8 v0 = *(const bf16x8*)(v_ws + rowb * DOUT + c0);
    bf16x8 v1 = *(const bf16x8*)(v_ws + rowb * DOUT + c0 + 8);
    __syncthreads();                 // prior MFMA reads done
#pragma unroll
    for (int e = 0; e < 8; ++e) {
      KT[(c0 + e) * 40 + r]     = k0[e];
      KT[(c0 + 8 + e) * 40 + r] = k1[e];
      VT[(c0 + e) * 40 + r]     = v0[e];
      VT[(c0 + 8 + e) * 40 + r] = v1[e];
      ksa[e]     += bf2f(k0[e]);
      ksa[e + 8] += bf2f(k1[e]);
    }
    __syncthreads();
    bf16x8 af0 = *(const bf16x8*)(&KT[(w * 32 + lr) * 40 + lq * 8]);
    bf16x8 af1 = *(const bf16x8*)(&KT[(w * 32 + 16 + lr) * 40 + lq * 8]);
#pragma unroll
    for (int ct = 0; ct < 8; ++ct) {
      bf16x8 bf = *(const bf16x8*)(&VT[(ct * 16 + lr) * 40 + lq * 8]);
      acc[0][ct] = MFMA16(af0, bf, acc[0][ct]);
      acc[1][ct] = MFMA16(af1, bf, acc[1][ct]);
    }
  }

  // --- partial KV store (f32, [i][j] per block) ---
  float* kvp = kv_part + (size_t)blockIdx.x * 16384;
#pragma unroll
  for (int rt = 0; rt < 2; ++rt)
#pragma unroll
    for (int ct = 0; ct < 8; ++ct)
#pragma unroll
      for (int f = 0; f < 4; ++f) {
        int i = w * 32 + rt * 16 + lq * 4 + f;
        int j = ct * 16 + lr;
        kvp[i * 128 + j] = acc[rt][ct][f];
      }
  // --- ksum partial: reduce 32 r-threads per col via LDS ---
  __syncthreads();
#pragma unroll
  for (int e = 0; e < 16; ++e) kred[r][c0 + e] = ksa[e];
  __syncthreads();
  if (tid < 128) {
    float s = 0.f;
#pragma unroll
    for (int rr = 0; rr < 32; ++rr) s += kred[rr][tid];
    ksum_part[blockIdx.x * 128 + tid] = s;
  }
}

// ---------------------------------------------------------------------------
// Kernel 4: reduce 256 KV partials -> kvT bf16 pre-swizzled; reduce ksum.
// Grid 65 x 256; lane-contiguous (coalesced) reduction.
// ---------------------------------------------------------------------------
__global__ void reduce_kv(const float* __restrict__ kv_part,
                          const float* __restrict__ ksum_part,
                          short* __restrict__ kvT, float* __restrict__ ksum) {
  if (blockIdx.x < 64) {
    int e = blockIdx.x * 256 + threadIdx.x;   // 0..16383
    float s = 0.f;
#pragma unroll 8
    for (int p = 0; p < 256; ++p) s += kv_part[(size_t)p * 16384 + e];
    int i = e >> 7, j = e & 127;
    kvT[j * 128 + (i ^ ((j & 7) << 3))] = f2bf(s);
  } else {
    if (threadIdx.x < 128) {
      float s = 0.f;
#pragma unroll 8
      for (int p = 0; p < 256; ++p) s += ksum_part[p * 128 + threadIdx.x];
      ksum[threadIdx.x] = s;
    }
  }
}

// ---------------------------------------------------------------------------
// Kernel 5: out = elu( (Q@KV) / (Q@ksum) ). 3125 x 256 (4 waves, 16 rows ea).
// ---------------------------------------------------------------------------
__global__ __launch_bounds__(256, 4) void pass_c(
    const short* __restrict__ q_ws, const short* __restrict__ kvT,
    const float* __restrict__ ksum, float* __restrict__ out) {
  __shared__ __attribute__((aligned(16))) char smem[33024];
  const int tid = threadIdx.x;
  const int w  = tid >> 6, l = tid & 63, lq = l >> 4, lr = l & 15;
  const int rowbase = blockIdx.x * 64 + w * 16;

#pragma unroll
  for (int q = 0; q < 8; ++q) {
    int cc = q * 256 + tid;
    *(bf16x8*)(smem + cc * 16) = *(const bf16x8*)(kvT + cc * 8);
  }

  bf16x8 qa[4];
  float d = 0.f;
  const short* qrow = q_ws + (size_t)(rowbase + lr) * DOUT + lq * 8;
#pragma unroll
  for (int ks = 0; ks < 4; ++ks) {
    qa[ks] = *(const bf16x8*)(qrow + ks * 32);
    f32x4 k0 = *(const f32x4*)(ksum + ks * 32 + lq * 8);
    f32x4 k1 = *(const f32x4*)(ksum + ks * 32 + lq * 8 + 4);
#pragma unroll
    for (int e = 0; e < 4; ++e) d += bf2f(qa[ks][e]) * k0[e];
#pragma unroll
    for (int e = 0; e < 4; ++e) d += bf2f(qa[ks][e + 4]) * k1[e];
  }
  d += __shfl_xor(d, 16);
  d += __shfl_xor(d, 32);
  float* dlds = (float*)(smem + 32768);
  if (l < 16) dlds[w * 16 + lr] = d;
  __syncthreads();

  f32x4 acc[8];
#pragma unroll
  for (int jt = 0; jt < 8; ++jt) acc[jt] = (f32x4){0.f, 0.f, 0.f, 0.f};
#pragma unroll
  for (int ks = 0; ks < 4; ++ks) {
#pragma unroll
    for (int jt = 0; jt < 8; ++jt) {
      const int j    = jt * 16 + lr;
      const int slot = (ks * 4 + lq) ^ (lr & 7);
      bf16x8 bv = *(const bf16x8*)(smem + j * 256 + (slot << 4));
      acc[jt] = MFMA16(qa[ks], bv, acc[jt]);
    }
  }
  float z[4];
#pragma unroll
  for (int f = 0; f < 4; ++f) z[f] = 1.f / dlds[w * 16 + lq * 4 + f];
#pragma unroll
  for (int jt = 0; jt < 8; ++jt) {
#pragma unroll
    for (int f = 0; f < 4; ++f) {
      float v = acc[jt][f] * z[f];
      v = (v > 0.f) ? v : (__expf(v) - 1.f);
      out[(size_t)(rowbase + lq * 4 + f) * DOUT + jt * 16 + lr] = v;
    }
  }
}

// ---------------------------------------------------------------------------
// Workspace layout (bytes), total ~170.9 MB:
//   [0,           51200000)   q_ws      bf16 N x 128
//   [51200000,   102400000)   k_ws      bf16 N x 128
//   [102400000,  153600000)   v_ws      bf16 N x 128
//   [153600000,  153993216)   wt        bf16 image 3 x 128 x 512 (swizzled)
//   [153993216,  170770432)   kv_part   f32 256 x 128 x 128
//   [170770432,  170901504)   ksum_part f32 256 x 128
//   [170901504,  170934272)   kvT       bf16 128 x 128 (pre-swizzled)
//   [170934272,  170934784)   ksum      f32 128
// ---------------------------------------------------------------------------
extern "C" void kernel_launch(void* const* d_in, const int* in_sizes, int n_in,
                              void* d_out, int out_size, void* d_ws, size_t ws_size,
                              hipStream_t stream) {
  const float* h  = (const float*)d_in[0];
  const float* wq = (const float*)d_in[1];
  const float* wk = (const float*)d_in[2];
  const float* wv = (const float*)d_in[3];
  char* ws = (char*)d_ws;
  short* q_ws      = (short*)(ws);
  short* k_ws      = (short*)(ws + 51200000);
  short* v_ws      = (short*)(ws + 102400000);
  short* wt        = (short*)(ws + 153600000);
  float* kv_part   = (float*)(ws + 153993216);
  float* ksum_part = (float*)(ws + 170770432);
  short* kvT       = (short*)(ws + 170901504);
  float* ksum      = (float*)(ws + 170934272);
  float* out       = (float*)d_out;

  hipFuncSetAttribute((const void*)pass_a,
                      hipFuncAttributeMaxDynamicSharedMemorySize, 131072);

  prep_wt<<<dim3(96), dim3(256), 0, stream>>>(wq, wk, wv, wt);
  pass_a<<<dim3(2352), dim3(512), 131072, stream>>>(h, wt, q_ws, k_ws, v_ws);
  pass_b<<<dim3(256), dim3(256), 0, stream>>>(k_ws, v_ws, kv_part, ksum_part);
  reduce_kv<<<dim3(65), dim3(256), 0, stream>>>(kv_part, ksum_part, kvT, ksum);
  pass_c<<<dim3(3125), dim3(256), 0, stream>>>(q_ws, kvT, ksum, out);
}